// Round 6
// baseline (602.811 us; speedup 1.0000x reference)
//
#include <hip/hip_runtime.h>
#include <math.h>

#define BATCH  32
#define NPTS   8192
#define NGROUP 512
#define MSIZE  32

#define FPS_THREADS 512
#define SXYZ_FLOATS (NPTS * 3)
#define DYN_LDS_BYTES (SXYZ_FLOATS * 4)

#define NBLOCKS      256
#define WORKER_BLKS  (NBLOCKS - BATCH)          // 224
#define WORKER_WAVES (WORKER_BLKS * 8)          // 1792
#define WPB          (WORKER_WAVES / BATCH)     // 56 worker waves per batch
#define PROG_STRIDE  16                          // u32s (64B) per batch flag

typedef float v2f __attribute__((ext_vector_type(2)));

// ---- DPP helpers (CTRL compile-time const) --------------------------------
template<int CTRL>
__device__ __forceinline__ float dpp_max_f32(float x) {
    int o = __builtin_amdgcn_update_dpp(0, __float_as_int(x), CTRL, 0xF, 0xF, true);
    float f = __int_as_float(o);
    return x > f ? x : f;
}
template<int CTRL>
__device__ __forceinline__ unsigned dpp_min_u32_full(unsigned x) {
    unsigned o = (unsigned)__builtin_amdgcn_update_dpp(0, (int)x, CTRL, 0xF, 0xF, true);
    return o < x ? o : x;
}

// ---------------------------------------------------------------------------
// FPS body: EXACT round-0 skeleton (best measured 463.7 µs; r1/r3/r4 proved
// every deviation neutral-to-negative). Only t0's post-barrier tail differs:
// center stores are agent-scope relaxed atomics (coherent channel for the
// worker blocks) and every 8th step t0 release-publishes prog[b]=g+1.
// All centers are stored by t0 itself -> same-thread program order makes the
// release cover them; agent scope handles cross-XCD visibility (G16).
// r3 measured t0's post-barrier tail as off-critical-path (store-hoist was
// neutral), so the added publish cost is bounded (~vmcnt drain every 8 steps
// on wave 0 only).
// ---------------------------------------------------------------------------
__device__ __forceinline__ void fps_body(const float* __restrict__ xyz,
                                         float* __restrict__ out_center,
                                         float* __restrict__ out_fps,
                                         unsigned* __restrict__ prog,
                                         float* sxyz)
{
#pragma clang fp contract(off)
    __shared__ unsigned long long gkey[3];

    const int b    = blockIdx.x;
    const int t    = threadIdx.x;
    const int lane = t & 63;
    const float* bp = xyz + (size_t)b * NPTS * 3;
    const float4* bp4 = reinterpret_cast<const float4*>(bp);
    float4* s4 = reinterpret_cast<float4*>(sxyz);

    v2f px2[8], py2[8], pz2[8], dist2[8];
    {
        float f[48];
        #pragma unroll
        for (int q = 0; q < 12; ++q) {
            float4 v = bp4[t * 12 + q];
            s4[t * 12 + q] = v;
            f[q*4+0] = v.x; f[q*4+1] = v.y; f[q*4+2] = v.z; f[q*4+3] = v.w;
        }
        #pragma unroll
        for (int j = 0; j < 8; ++j) {
            px2[j] = (v2f){f[6*j+0], f[6*j+3]};
            py2[j] = (v2f){f[6*j+1], f[6*j+4]};
            pz2[j] = (v2f){f[6*j+2], f[6*j+5]};
            dist2[j] = (v2f){INFINITY, INFINITY};
        }
    }
    if (t == 0) { gkey[0] = 0; gkey[1] = 0; gkey[2] = 0; }
    __syncthreads();   // sxyz + gkey visible

    if (t == 0) {
        out_fps[(size_t)b * NGROUP] = 0.0f;
        __hip_atomic_store(&out_center[(size_t)(b*NGROUP)*3 + 0], sxyz[0],
                           __ATOMIC_RELAXED, __HIP_MEMORY_SCOPE_AGENT);
        __hip_atomic_store(&out_center[(size_t)(b*NGROUP)*3 + 1], sxyz[1],
                           __ATOMIC_RELAXED, __HIP_MEMORY_SCOPE_AGENT);
        __hip_atomic_store(&out_center[(size_t)(b*NGROUP)*3 + 2], sxyz[2],
                           __ATOMIC_RELAXED, __HIP_MEMORY_SCOPE_AGENT);
    }

    int last = 0;
    for (int g = 1; g < NGROUP; ++g) {
        const int slot = g % 3;
        const int nxt  = (g + 1) % 3;
        float lx = sxyz[last*3 + 0];
        float ly = sxyz[last*3 + 1];
        float lz = sxyz[last*3 + 2];

        #pragma unroll
        for (int j = 0; j < 8; ++j) {
            v2f dx = px2[j] - lx;
            v2f dy = py2[j] - ly;
            v2f dz = pz2[j] - lz;
            v2f t1 = dx * dx;
            v2f t2 = dy * dy;
            v2f t3 = dz * dz;
            v2f s  = t1 + t2;
            v2f d  = s + t3;
            dist2[j] = __builtin_elementwise_min(dist2[j], d);
        }
        v2f mm0 = __builtin_elementwise_max(dist2[0], dist2[1]);
        v2f mm1 = __builtin_elementwise_max(dist2[2], dist2[3]);
        v2f mm2 = __builtin_elementwise_max(dist2[4], dist2[5]);
        v2f mm3 = __builtin_elementwise_max(dist2[6], dist2[7]);
        v2f mma = __builtin_elementwise_max(mm0, mm1);
        v2f mmb = __builtin_elementwise_max(mm2, mm3);
        v2f mmc = __builtin_elementwise_max(mma, mmb);
        float m_t = fmaxf(mmc.x, mmc.y);

        float m = m_t;
        m = dpp_max_f32<0xB1>(m);     // quad_perm xor1
        m = dpp_max_f32<0x4E>(m);     // quad_perm xor2
        m = dpp_max_f32<0x141>(m);    // row_half_mirror
        m = dpp_max_f32<0x140>(m);    // row_mirror
        m = dpp_max_f32<0x142>(m);    // row_bcast15
        m = dpp_max_f32<0x143>(m);    // row_bcast31
        float wmax = __int_as_float(__builtin_amdgcn_readlane(__float_as_int(m), 63));

        unsigned long long mask = __ballot(m_t == wmax);
        int l = __ffsll((long long)mask) - 1;

        unsigned lj = 0;
        #pragma unroll
        for (int j = 15; j >= 0; --j) {
            float dj = (j & 1) ? dist2[j >> 1].y : dist2[j >> 1].x;
            lj = (dj == wmax) ? (unsigned)j : lj;
        }
        unsigned idx = ((unsigned)t << 4) | lj;
        unsigned widx = (unsigned)__builtin_amdgcn_readlane((int)idx, l);

        if (lane == 63) {
            unsigned long long key =
                (((unsigned long long)__float_as_uint(wmax)) << 32) | (unsigned)~widx;
            atomicMax(&gkey[slot], key);
            if (t == 63) gkey[nxt] = 0;   // reset slot for step g+1 (pre-barrier)
        }
        __syncthreads();                  // the ONE barrier

        unsigned long long kq = gkey[slot];
        int fi = (int)(~(unsigned)kq);
        last = fi;
        if (t == 0) {
            out_fps[(size_t)b * NGROUP + g] = (float)fi;
            const size_t o3 = ((size_t)(b * NGROUP + g)) * 3;
            __hip_atomic_store(&out_center[o3 + 0], sxyz[fi*3 + 0],
                               __ATOMIC_RELAXED, __HIP_MEMORY_SCOPE_AGENT);
            __hip_atomic_store(&out_center[o3 + 1], sxyz[fi*3 + 1],
                               __ATOMIC_RELAXED, __HIP_MEMORY_SCOPE_AGENT);
            __hip_atomic_store(&out_center[o3 + 2], sxyz[fi*3 + 2],
                               __ATOMIC_RELAXED, __HIP_MEMORY_SCOPE_AGENT);
            if ((g & 7) == 7)   // g=511 included (511&7==7) -> prog=512 at end
                __hip_atomic_store(&prog[b * PROG_STRIDE], (unsigned)(g + 1),
                                   __ATOMIC_RELEASE, __HIP_MEMORY_SCOPE_AGENT);
        }
    }
}

// ---------------------------------------------------------------------------
// kNN one-group body: VERBATIM round-0 math (known-good, bit-identical).
// ---------------------------------------------------------------------------
__device__ __forceinline__ void knn_one_group(const float* __restrict__ bp,
                                              const float4* __restrict__ bp4,
                                              int gid, int lane,
                                              float cx, float cy, float cz,
                                              float* __restrict__ out_nbhd)
{
    unsigned kl[4];
    #pragma unroll
    for (int k = 0; k < 4; ++k) kl[k] = 0xFFFFFFFFu;

    for (int c = 0; c < 32; ++c) {
        int f4 = c * 192 + lane * 3;
        float4 a  = bp4[f4+0];
        float4 bq = bp4[f4+1];
        float4 cq = bp4[f4+2];
        unsigned p0 = (unsigned)(c * 256 + lane * 4);
        v2f xA = (v2f){a.x,  a.w},  yA = (v2f){a.y,  bq.x}, zA = (v2f){a.z,  bq.y};
        v2f xB = (v2f){bq.z, cq.y}, yB = (v2f){bq.w, cq.z}, zB = (v2f){cq.x, cq.w};
        v2f dxA = xA - cx, dyA = yA - cy, dzA = zA - cz;
        v2f dxB = xB - cx, dyB = yB - cy, dzB = zB - cz;
        v2f dA = dxA*dxA + dyA*dyA + dzA*dzA;
        v2f dB = dxB*dxB + dyB*dyB + dzB*dzB;
        float ds[4] = {dA.x, dA.y, dB.x, dB.y};
        #pragma unroll
        for (int k = 0; k < 4; ++k) {
            unsigned key = (__float_as_uint(ds[k]) & 0xFFFFE000u) | (p0 + k);
            if (key < kl[3]) {
                kl[3] = key;
                #pragma unroll
                for (int q = 3; q > 0; --q) {
                    if (kl[q] < kl[q-1]) {
                        unsigned tk = kl[q]; kl[q] = kl[q-1]; kl[q-1] = tk;
                    }
                }
            }
        }
    }

    int keep = 0;
    #pragma unroll 1
    for (int r = 0; r < MSIZE; ++r) {
        unsigned k = kl[0];
        k = dpp_min_u32_full<0xB1>(k);
        k = dpp_min_u32_full<0x4E>(k);
        k = dpp_min_u32_full<0x141>(k);
        k = dpp_min_u32_full<0x140>(k);
        {
            unsigned o = __shfl_xor(k, 16);
            k = o < k ? o : k;
            o = __shfl_xor(k, 32);
            k = o < k ? o : k;
        }
        if (lane == r) keep = (int)(k & 0x1FFFu);
        if (kl[0] == k) {
            kl[0] = kl[1]; kl[1] = kl[2]; kl[2] = kl[3];
            kl[3] = 0xFFFFFFFFu;
        }
    }

    if (lane < MSIZE) {
        size_t o = ((size_t)gid * MSIZE + lane) * 3;
        float x = bp[keep*3+0], y = bp[keep*3+1], z = bp[keep*3+2];
        out_nbhd[o+0] = x - cx;
        out_nbhd[o+1] = y - cy;
        out_nbhd[o+2] = z - cz;
    }
}

// ---------------------------------------------------------------------------
// Fused producer-consumer kernel. 256 blocks x 512 thr, 96KB dyn-LDS each
// (forces 1 block/CU; cooperative launch guarantees all co-resident ->
// deadlock-free). Blocks 0..31 = fps producers (one per batch). Blocks
// 32..255 = 1792 knn worker waves; wave ww serves batch b=ww&31, groups
// g = (ww>>5) + 56k (monotone per wave; bijective over all 16384 groups).
// Worker waits: acquire-poll prog[b] with s_sleep backoff; centers read via
// agent relaxed atomic loads (paired with producer's atomic stores; the
// release/acquire on prog establishes happens-before).
// ---------------------------------------------------------------------------
__global__ __launch_bounds__(FPS_THREADS, 2)
void fused_kernel(const float* __restrict__ xyz,
                  float* __restrict__ out_center,
                  float* __restrict__ out_fps,
                  float* __restrict__ out_nbhd,
                  unsigned* __restrict__ prog)
{
    extern __shared__ float sxyz[];   // used by fps blocks only

    if (blockIdx.x < BATCH) {
        fps_body(xyz, out_center, out_fps, prog, sxyz);
        return;
    }

    // ---- knn worker path ----
    const int t    = threadIdx.x;
    const int lane = t & 63;
    const int wid  = t >> 6;
    const int ww   = (blockIdx.x - BATCH) * 8 + wid;   // 0..1791
    const int b    = ww & 31;
    const int g0   = ww >> 5;                          // 0..55
    const float* bp = xyz + (size_t)b * NPTS * 3;
    const float4* bp4 = reinterpret_cast<const float4*>(bp);

    for (int g = g0; g < NGROUP; g += WPB) {
        // wait until center g is published (prog[b] > g)
        while ((int)__hip_atomic_load(&prog[b * PROG_STRIDE],
                                      __ATOMIC_ACQUIRE, __HIP_MEMORY_SCOPE_AGENT) <= g)
            __builtin_amdgcn_s_sleep(8);

        const int gid = b * NGROUP + g;
        float cx = __hip_atomic_load(&out_center[(size_t)gid*3+0],
                                     __ATOMIC_RELAXED, __HIP_MEMORY_SCOPE_AGENT);
        float cy = __hip_atomic_load(&out_center[(size_t)gid*3+1],
                                     __ATOMIC_RELAXED, __HIP_MEMORY_SCOPE_AGENT);
        float cz = __hip_atomic_load(&out_center[(size_t)gid*3+2],
                                     __ATOMIC_RELAXED, __HIP_MEMORY_SCOPE_AGENT);
        knn_one_group(bp, bp4, gid, lane, cx, cy, cz, out_nbhd);
    }
}

// ---------------------------------------------------------------------------
// Fallback path: EXACT round-0 two-kernel pipeline (577 µs), used if
// cooperative launch is unavailable or workspace missing.
// ---------------------------------------------------------------------------
__global__ __launch_bounds__(FPS_THREADS, 2)
void fps_kernel(const float* __restrict__ xyz,
                float* __restrict__ out_center,
                float* __restrict__ out_fps)
{
#pragma clang fp contract(off)
    extern __shared__ float sxyz[];
    __shared__ unsigned long long gkey[3];

    const int b    = blockIdx.x;
    const int t    = threadIdx.x;
    const int lane = t & 63;
    const float* bp = xyz + (size_t)b * NPTS * 3;
    const float4* bp4 = reinterpret_cast<const float4*>(bp);
    float4* s4 = reinterpret_cast<float4*>(sxyz);

    v2f px2[8], py2[8], pz2[8], dist2[8];
    {
        float f[48];
        #pragma unroll
        for (int q = 0; q < 12; ++q) {
            float4 v = bp4[t * 12 + q];
            s4[t * 12 + q] = v;
            f[q*4+0] = v.x; f[q*4+1] = v.y; f[q*4+2] = v.z; f[q*4+3] = v.w;
        }
        #pragma unroll
        for (int j = 0; j < 8; ++j) {
            px2[j] = (v2f){f[6*j+0], f[6*j+3]};
            py2[j] = (v2f){f[6*j+1], f[6*j+4]};
            pz2[j] = (v2f){f[6*j+2], f[6*j+5]};
            dist2[j] = (v2f){INFINITY, INFINITY};
        }
    }
    if (t == 0) { gkey[0] = 0; gkey[1] = 0; gkey[2] = 0; }
    __syncthreads();

    if (t == 0) {
        out_fps[(size_t)b * NGROUP] = 0.0f;
        out_center[(size_t)(b * NGROUP) * 3 + 0] = sxyz[0];
        out_center[(size_t)(b * NGROUP) * 3 + 1] = sxyz[1];
        out_center[(size_t)(b * NGROUP) * 3 + 2] = sxyz[2];
    }

    int last = 0;
    for (int g = 1; g < NGROUP; ++g) {
        const int slot = g % 3;
        const int nxt  = (g + 1) % 3;
        float lx = sxyz[last*3 + 0];
        float ly = sxyz[last*3 + 1];
        float lz = sxyz[last*3 + 2];

        #pragma unroll
        for (int j = 0; j < 8; ++j) {
            v2f dx = px2[j] - lx;
            v2f dy = py2[j] - ly;
            v2f dz = pz2[j] - lz;
            v2f t1 = dx * dx;
            v2f t2 = dy * dy;
            v2f t3 = dz * dz;
            v2f s  = t1 + t2;
            v2f d  = s + t3;
            dist2[j] = __builtin_elementwise_min(dist2[j], d);
        }
        v2f mm0 = __builtin_elementwise_max(dist2[0], dist2[1]);
        v2f mm1 = __builtin_elementwise_max(dist2[2], dist2[3]);
        v2f mm2 = __builtin_elementwise_max(dist2[4], dist2[5]);
        v2f mm3 = __builtin_elementwise_max(dist2[6], dist2[7]);
        v2f mma = __builtin_elementwise_max(mm0, mm1);
        v2f mmb = __builtin_elementwise_max(mm2, mm3);
        v2f mmc = __builtin_elementwise_max(mma, mmb);
        float m_t = fmaxf(mmc.x, mmc.y);

        float m = m_t;
        m = dpp_max_f32<0xB1>(m);
        m = dpp_max_f32<0x4E>(m);
        m = dpp_max_f32<0x141>(m);
        m = dpp_max_f32<0x140>(m);
        m = dpp_max_f32<0x142>(m);
        m = dpp_max_f32<0x143>(m);
        float wmax = __int_as_float(__builtin_amdgcn_readlane(__float_as_int(m), 63));

        unsigned long long mask = __ballot(m_t == wmax);
        int l = __ffsll((long long)mask) - 1;

        unsigned lj = 0;
        #pragma unroll
        for (int j = 15; j >= 0; --j) {
            float dj = (j & 1) ? dist2[j >> 1].y : dist2[j >> 1].x;
            lj = (dj == wmax) ? (unsigned)j : lj;
        }
        unsigned idx = ((unsigned)t << 4) | lj;
        unsigned widx = (unsigned)__builtin_amdgcn_readlane((int)idx, l);

        if (lane == 63) {
            unsigned long long key =
                (((unsigned long long)__float_as_uint(wmax)) << 32) | (unsigned)~widx;
            atomicMax(&gkey[slot], key);
            if (t == 63) gkey[nxt] = 0;
        }
        __syncthreads();

        unsigned long long kq = gkey[slot];
        int fi = (int)(~(unsigned)kq);
        last = fi;
        if (t == 0) {
            out_fps[(size_t)b * NGROUP + g] = (float)fi;
            out_center[((size_t)(b * NGROUP + g)) * 3 + 0] = sxyz[fi*3 + 0];
            out_center[((size_t)(b * NGROUP + g)) * 3 + 1] = sxyz[fi*3 + 1];
            out_center[((size_t)(b * NGROUP + g)) * 3 + 2] = sxyz[fi*3 + 2];
        }
    }
}

__global__ __launch_bounds__(256)
void knn_kernel(const float* __restrict__ xyz,
                const float* __restrict__ center,
                float* __restrict__ out_nbhd)
{
    const int lane = threadIdx.x & 63;
    const int gid  = blockIdx.x * 4 + (threadIdx.x >> 6);
    const int b    = gid >> 9;
    const float* bp = xyz + (size_t)b * NPTS * 3;
    const float4* bp4 = reinterpret_cast<const float4*>(bp);
    const float cx = center[(size_t)gid*3+0];
    const float cy = center[(size_t)gid*3+1];
    const float cz = center[(size_t)gid*3+2];
    knn_one_group(bp, bp4, gid, lane, cx, cy, cz, out_nbhd);
}

// ---------------------------------------------------------------------------
extern "C" void kernel_launch(void* const* d_in, const int* in_sizes, int n_in,
                              void* d_out, int out_size, void* d_ws, size_t ws_size,
                              hipStream_t stream)
{
    const float* xyz = (const float*)d_in[0];
    float* out        = (float*)d_out;
    float* out_nbhd   = out;                                    // 32*512*32*3
    float* out_center = out + (size_t)BATCH*NGROUP*MSIZE*3;     // 32*512*3
    float* out_fps    = out_center + (size_t)BATCH*NGROUP*3;    // 32*512

    hipFuncSetAttribute(reinterpret_cast<const void*>(fused_kernel),
                        hipFuncAttributeMaxDynamicSharedMemorySize,
                        DYN_LDS_BYTES);
    hipFuncSetAttribute(reinterpret_cast<const void*>(fps_kernel),
                        hipFuncAttributeMaxDynamicSharedMemorySize,
                        DYN_LDS_BYTES);

    bool fused_ok = false;
    if (d_ws != nullptr && ws_size >= (size_t)BATCH * PROG_STRIDE * sizeof(unsigned)) {
        unsigned* prog = (unsigned*)d_ws;
        // zero progress flags (captured in-stream; re-zeroed every graph replay)
        hipMemsetAsync(prog, 0, (size_t)BATCH * PROG_STRIDE * sizeof(unsigned), stream);

        const float* a_xyz = xyz;
        float* a_oc = out_center; float* a_of = out_fps; float* a_on = out_nbhd;
        unsigned* a_pr = prog;
        void* args[5] = {(void*)&a_xyz, (void*)&a_oc, (void*)&a_of,
                         (void*)&a_on, (void*)&a_pr};
        hipError_t e = hipLaunchCooperativeKernel(
            reinterpret_cast<const void*>(fused_kernel),
            dim3(NBLOCKS), dim3(FPS_THREADS), args, DYN_LDS_BYTES, stream);
        fused_ok = (e == hipSuccess);
    }

    if (!fused_ok) {
        // fallback: proven round-0 two-kernel path
        fps_kernel<<<dim3(BATCH), dim3(FPS_THREADS), DYN_LDS_BYTES, stream>>>(xyz, out_center, out_fps);
        knn_kernel<<<dim3(BATCH*NGROUP/4), dim3(256), 0, stream>>>(xyz, out_center, out_nbhd);
    }
}